// Round 8
// baseline (110.221 us; speedup 1.0000x reference)
//
#include <hip/hip_runtime.h>
#include <math.h>

#define NT 365
#define NS 2048
#define NH 64
#define NG 128
#define NW 513      // nh*8+1
#define WSTR 520    // padded row stride for w buffer
#define FTR 368     // padded per-site forcing row length (float4s), 16B-aligned

__device__ __forceinline__ float sigmoidf_(float x) {
    return 1.0f / (1.0f + __expf(-x));
}

// ---------------- Kernel P: fused prep = gemm (blocks 0..255) + forcing ------
// forcing now writes TRANSPOSED: f[s][t] (row stride FTR float4s) so the scan
// streams contiguous per-site rows. Block layout: 16 sites x 16 phases.
__global__ __launch_bounds__(256) void prep_kernel(const float* __restrict__ xc,
                                                   const float* __restrict__ Wm,
                                                   const float* __restrict__ bv,
                                                   float* __restrict__ w,
                                                   const float* __restrict__ x,
                                                   float* __restrict__ f) {
    __shared__ float xcs[64][132];  // +4 pad: breaks bank conflict on column reads
    __shared__ float Wsh[64][132];
    const int tid = threadIdx.x;

    if (blockIdx.x >= 256) {
        // ---- forcing branch: (P,E,T1,T2) -> (Ps,Pl,E,relu(Ta)), transposed --
        const int b = blockIdx.x - 256;        // 0..127
        const int site16 = tid >> 4;           // 0..15
        const int phase  = tid & 15;
        const int s = b * 16 + site16;
        const float4* xp = (const float4*)x;
        float4* fpo = (float4*)f + (size_t)s * FTR;
        for (int tt = phase; tt < NT; tt += 16) {
            float4 v = xp[(size_t)tt * NS + s];       // 16 sites @ fixed t: 256B
            float P = v.x, E = v.y, T1 = v.z, T2 = v.w;
            float Ta = 0.5f * (T1 + T2);
            float rP;
            if (T2 <= 0.0f)       rP = 0.0f;          // mask0 wins (ref order)
            else if (T1 >= 0.0f)  rP = 1.0f;
            else                  rP = 1.0f - acosf((T1 + T2) / (T2 - T1)) * (1.0f / 3.1415f);
            float Ps = (1.0f - rP) * P;
            float Pl = rP * P;
            fpo[tt] = make_float4(Ps, Pl, E, fmaxf(Ta, 0.0f)); // 16 t @ fixed s: 256B
        }
        return;
    }

    // ---- gemm branch: w = xc @ W^T + b; 64x64 tile, K=128 in LDS ----
    const int sTile = (blockIdx.x >> 3) * 64;                // 32 s-tiles
    const int by = blockIdx.x & 7;
    const int jt = (by >= 2) ? by + 1 : by;                  // skip unused j-tile 2
    const int jTile = jt * 64;

    for (int i = 0; i < 8; i++) {
        int f4  = tid + i * 256;
        int row = f4 >> 5;
        int c4  = (f4 & 31) * 4;
        float4 v = ((const float4*)(xc + (size_t)(sTile + row) * NG))[f4 & 31];
        xcs[row][c4] = v.x; xcs[row][c4 + 1] = v.y; xcs[row][c4 + 2] = v.z; xcs[row][c4 + 3] = v.w;
        int jr = jTile + row;
        float4 wv = make_float4(0.f, 0.f, 0.f, 0.f);
        if (jr < NW) wv = ((const float4*)(Wm + (size_t)jr * NG))[f4 & 31];
        Wsh[row][c4] = wv.x; Wsh[row][c4 + 1] = wv.y; Wsh[row][c4 + 2] = wv.z; Wsh[row][c4 + 3] = wv.w;
    }
    __syncthreads();

    const int tx = tid & 15, ty = tid >> 4;
    float acc[4][4] = {};
#pragma unroll 4
    for (int k = 0; k < 128; k++) {
        float a0 = xcs[ty][k], a1 = xcs[ty + 16][k], a2 = xcs[ty + 32][k], a3 = xcs[ty + 48][k];
        float b0 = Wsh[tx][k], b1 = Wsh[tx + 16][k], b2 = Wsh[tx + 32][k], b3 = Wsh[tx + 48][k];
        acc[0][0] += a0 * b0; acc[0][1] += a0 * b1; acc[0][2] += a0 * b2; acc[0][3] += a0 * b3;
        acc[1][0] += a1 * b0; acc[1][1] += a1 * b1; acc[1][2] += a1 * b2; acc[1][3] += a1 * b3;
        acc[2][0] += a2 * b0; acc[2][1] += a2 * b1; acc[2][2] += a2 * b2; acc[2][3] += a2 * b3;
        acc[3][0] += a3 * b0; acc[3][1] += a3 * b1; acc[3][2] += a3 * b2; acc[3][3] += a3 * b3;
    }
#pragma unroll
    for (int i = 0; i < 4; i++) {
        int s = sTile + ty + 16 * i;
#pragma unroll
        for (int j = 0; j < 4; j++) {
            int jj = jTile + tx + 16 * j;
            if (jj < NW) w[(size_t)s * WSTR + jj] = acc[i][j] + bv[jj];
        }
    }
}

// ---------------- Kernel C: scan, one site per wave ---------------------------
// PRE: forcing rows are contiguous per site -> loads are saddr(uniform base,
// +512B per superblock) + voff(s*5888, fixed laundered VGPR) + imm((tl+8)*16):
// ZERO per-step address VALU, 4 steps share each 64B line (miss rate /4).
// 32-step superblocks fully unrolled; per-wave [64][33] LDS y-tile;
// transpose-reduce every 32 steps (imm-offset ds_read_b32, no cross-lane).
template <bool PRE>
__global__ __launch_bounds__(256) void scan_kernel(const float* __restrict__ fx,
                                                   const float* __restrict__ w,
                                                   float* __restrict__ Y) {
    __shared__ float ybuf[4][64][33];   // 33,792 B per block
    const int wave = threadIdx.x >> 6;
    const int lane = threadIdx.x & 63;
    const int s = blockIdx.x * 4 + wave;
    const float* wr = w + (size_t)s * WSTR;

    // gate parameters (lane = hidden unit) — scalar loads OK (setup only)
    float gm = __expf(wr[lane]) + 1.0f;
    float geN = -2.0f * sigmoidf_(wr[64 + lane]);
    float k0 = sigmoidf_(wr[192 + lane]);
    float w4 = wr[256 + lane];
    float k1 = sigmoidf_(w4);
    float k2 = sigmoidf_(wr[320 + lane]);
    float gl = __expf(wr[384 + lane]);
    float kb = sigmoidf_(wr[448 + lane]) * 0.1f;
    float wl = wr[512];
    float qb = fmaxf(wl, 0.0f) * (1.0f / (float)NH);
    float vi = sigmoidf_(wl);

    // softmax over lanes -> ga
    float m = w4;
#pragma unroll
    for (int off = 32; off; off >>= 1) m = fmaxf(m, __shfl_xor(m, off));
    float ex = __expf(w4 - m);
    float sum = ex;
#pragma unroll
    for (int off = 32; off; off >>= 1) sum += __shfl_xor(sum, off);
    float ga = ex / sum;

    // folded coefficients
    float c0   = k0 * ga;
    float c1   = k1 * (1.0f - kb) * ga;
    float c2   = k2 * ga;
    float k0c  = 1.0f - k0;
    float k2c  = 1.0f - k2;
    float glN  = -gl;
    float viC  = 1.0f - vi;
    float k1kb = k1 * kb;    // G2 = fma(m1, k1kb, H2)
    float k1N  = -k1;        // H1 = min(fma(m1, k1N, G1), gl)

    float S0 = 0.f, H0 = 0.f, H1 = 0.f, H2 = 0.f;

    const char* fB = (const char*)fx;          // uniform SGPR base
    // laundered per-site byte offset: PRE -> s*FTR*16 (row start); else s*16
    unsigned voff = PRE ? (unsigned)s * (FTR * 16u) : (unsigned)s * 16u;
    asm volatile("" : "+v"(voff));

    float4 vbuf[8];
#pragma unroll
    for (int b = 0; b < 8; b++) {
        if (PRE) vbuf[b] = *(const float4*)(fB + voff + b * 16);
        else     vbuf[b] = *(const float4*)(fB + (size_t)b * (NS * 16) + voff);
    }

    float* wp = &ybuf[wave][lane][0];                           // write: row h=lane
    const float* rp = &ybuf[wave][(lane >> 5) << 5][lane & 31]; // read: column

#define STEP_COMP(vv, tl)                                                      \
    {                                                                          \
        float Ps, Pl, E, TaR;                                                  \
        if (PRE) { Ps = vv.x; Pl = vv.y; E = vv.z; TaR = vv.w; }               \
        else {                                                                 \
            float P = vv.x; E = vv.y;                                          \
            float T1 = vv.z, T2 = vv.w;                                        \
            float Ta = 0.5f * (T1 + T2);                                       \
            float rP;                                                          \
            if (T2 <= 0.0f)      rP = 0.0f;                                    \
            else if (T1 >= 0.0f) rP = 1.0f;                                    \
            else rP = 1.0f - acosf((T1 + T2) / (T2 - T1)) * (1.0f / 3.1415f);  \
            Ps = (1.0f - rP) * P; Pl = rP * P; TaR = fmaxf(Ta, 0.0f);          \
        }                                                                      \
        float S   = S0 + Ps;                                                   \
        float Sm  = fminf(S0, gm * TaR);                                       \
        S0 = S - Sm;                                                           \
        float G1  = fmaxf(H1 + Sm + fmaf(E, geN, Pl * vi), 0.0f);              \
        float G0  = fmaxf(H0 + G1 + fmaf(Pl, viC, glN), 0.0f);                 \
        float m1  = fminf(G1, gl);                                             \
        float G2  = fmaf(m1, k1kb, H2);                                        \
        wp[tl] = fmaf(G0, c0, fmaf(m1, c1, G2 * c2));                          \
        H0 = G0 * k0c;                                                         \
        H1 = fminf(fmaf(m1, k1N, G1), gl);                                     \
        H2 = G2 * k2c;                                                         \
    }

#define TRRED(t0)                                                              \
    {                                                                          \
        float a0 = 0.f, a1 = 0.f, a2 = 0.f, a3 = 0.f;                          \
        _Pragma("unroll")                                                      \
        for (int j = 0; j < 32; j += 4) {                                      \
            a0 += rp[(size_t)j * 33];                                          \
            a1 += rp[(size_t)(j + 1) * 33];                                    \
            a2 += rp[(size_t)(j + 2) * 33];                                    \
            a3 += rp[(size_t)(j + 3) * 33];                                    \
        }                                                                      \
        float part = (a0 + a1) + (a2 + a3);                                    \
        float full = part + __shfl_xor(part, 32);                              \
        int t = (t0) + (lane & 31);                                            \
        if (lane < 32 && t < NT) Y[(size_t)t * NS + s] = full + qb;            \
    }

    // superblocks 0..10: prefetch t = sb*32 + tl + 8 <= 359 < NT
    for (int sb = 0; sb < 11; ++sb) {
        const char* fs = fB + sb * (32 * 16);       // uniform scalar advance
#pragma unroll
        for (int tl = 0; tl < 32; ++tl) {
            float4 v = vbuf[tl & 7];
            if (PRE)
                vbuf[tl & 7] = *(const float4*)(fs + voff + (tl + 8) * 16);
            else
                vbuf[tl & 7] = *(const float4*)(fB + (size_t)(sb * 32 + tl + 8) * (NS * 16) + voff);
            STEP_COMP(v, tl);
        }
        TRRED(sb * 32);
    }
    // tail superblock (t0=352): steps 352..383; stores masked to t<365;
    // prefetch t clamped to 364 at COMPILE TIME (tl is unrolled-const)
    {
        const int t0 = 352;
        const char* fs = fB + 11 * (32 * 16);
#pragma unroll
        for (int tl = 0; tl < 32; ++tl) {
            float4 v = vbuf[tl & 7];
            const int rel = (tl + 8 > 12) ? 12 : (tl + 8);   // 352+rel <= 364
            if (PRE)
                vbuf[tl & 7] = *(const float4*)(fs + voff + rel * 16);
            else
                vbuf[tl & 7] = *(const float4*)(fB + (size_t)(t0 + rel) * (NS * 16) + voff);
            STEP_COMP(v, tl);
        }
        TRRED(t0);
    }
#undef STEP_COMP
#undef TRRED
}

extern "C" void kernel_launch(void* const* d_in, const int* in_sizes, int n_in,
                              void* d_out, int out_size, void* d_ws, size_t ws_size,
                              hipStream_t stream) {
    const float* x  = (const float*)d_in[0];   // [NT, NS, 4]
    const float* xc = (const float*)d_in[1];   // [NS, NG]
    const float* Wm = (const float*)d_in[2];   // [NW, NG]
    const float* bv = (const float*)d_in[3];   // [NW]
    float* out = (float*)d_out;                // [NT, NS] fp32

    float* wbuf = (float*)d_ws;                                 // NS*WSTR floats
    size_t wbytes = (size_t)NS * WSTR * sizeof(float);          // 4,259,840 B
    float* fbuf = (float*)((char*)d_ws + wbytes);               // NS x FTR float4
    size_t need = wbytes + (size_t)NS * FTR * 16;               // ~16.3 MB

    if (ws_size >= need) {
        prep_kernel<<<256 + NS / 16, 256, 0, stream>>>(xc, Wm, bv, wbuf, x, fbuf);
        scan_kernel<true><<<NS / 4, 256, 0, stream>>>(fbuf, wbuf, out);
    } else {
        prep_kernel<<<256, 256, 0, stream>>>(xc, Wm, bv, wbuf, x, fbuf);  // gemm only
        scan_kernel<false><<<NS / 4, 256, 0, stream>>>(x, wbuf, out);
    }
}

// Round 9
// 110.147 us; speedup vs baseline: 1.0007x; 1.0007x over previous
//
#include <hip/hip_runtime.h>
#include <math.h>

#define NT 365
#define NS 2048
#define NH 64
#define NG 128
#define NW 513      // nh*8+1
#define WSTR 520    // padded row stride for w buffer
#define FTR 368     // padded per-site forcing row length (float4s)

__device__ __forceinline__ float sigmoidf_(float x) {
    return 1.0f / (1.0f + __expf(-x));
}

// ---------------- Kernel P: fused prep = gemm (blocks 0..255) + forcing ------
// forcing writes TRANSPOSED: f[s][t] (row stride FTR float4s) so the scan
// streams contiguous per-site rows. Block layout: 16 sites x 16 phases.
__global__ __launch_bounds__(256) void prep_kernel(const float* __restrict__ xc,
                                                   const float* __restrict__ Wm,
                                                   const float* __restrict__ bv,
                                                   float* __restrict__ w,
                                                   const float* __restrict__ x,
                                                   float* __restrict__ f) {
    __shared__ float xcs[64][132];  // +4 pad: breaks bank conflict on column reads
    __shared__ float Wsh[64][132];
    const int tid = threadIdx.x;

    if (blockIdx.x >= 256) {
        // ---- forcing branch: (P,E,T1,T2) -> (Ps,Pl,E,relu(Ta)), transposed --
        const int b = blockIdx.x - 256;        // 0..127
        const int site16 = tid >> 4;           // 0..15
        const int phase  = tid & 15;
        const int s = b * 16 + site16;
        const float4* xp = (const float4*)x;
        float4* fpo = (float4*)f + (size_t)s * FTR;
        for (int tt = phase; tt < NT; tt += 16) {
            float4 v = xp[(size_t)tt * NS + s];       // 16 sites @ fixed t: 256B
            float P = v.x, E = v.y, T1 = v.z, T2 = v.w;
            float Ta = 0.5f * (T1 + T2);
            float rP;
            if (T2 <= 0.0f)       rP = 0.0f;          // mask0 wins (ref order)
            else if (T1 >= 0.0f)  rP = 1.0f;
            else                  rP = 1.0f - acosf((T1 + T2) / (T2 - T1)) * (1.0f / 3.1415f);
            float Ps = (1.0f - rP) * P;
            float Pl = rP * P;
            fpo[tt] = make_float4(Ps, Pl, E, fmaxf(Ta, 0.0f)); // 16 t @ fixed s: 256B
        }
        return;
    }

    // ---- gemm branch: w = xc @ W^T + b; 64x64 tile, K=128 in LDS ----
    const int sTile = (blockIdx.x >> 3) * 64;                // 32 s-tiles
    const int by = blockIdx.x & 7;
    const int jt = (by >= 2) ? by + 1 : by;                  // skip unused j-tile 2
    const int jTile = jt * 64;

    for (int i = 0; i < 8; i++) {
        int f4  = tid + i * 256;
        int row = f4 >> 5;
        int c4  = (f4 & 31) * 4;
        float4 v = ((const float4*)(xc + (size_t)(sTile + row) * NG))[f4 & 31];
        xcs[row][c4] = v.x; xcs[row][c4 + 1] = v.y; xcs[row][c4 + 2] = v.z; xcs[row][c4 + 3] = v.w;
        int jr = jTile + row;
        float4 wv = make_float4(0.f, 0.f, 0.f, 0.f);
        if (jr < NW) wv = ((const float4*)(Wm + (size_t)jr * NG))[f4 & 31];
        Wsh[row][c4] = wv.x; Wsh[row][c4 + 1] = wv.y; Wsh[row][c4 + 2] = wv.z; Wsh[row][c4 + 3] = wv.w;
    }
    __syncthreads();

    const int tx = tid & 15, ty = tid >> 4;
    float acc[4][4] = {};
#pragma unroll 4
    for (int k = 0; k < 128; k++) {
        float a0 = xcs[ty][k], a1 = xcs[ty + 16][k], a2 = xcs[ty + 32][k], a3 = xcs[ty + 48][k];
        float b0 = Wsh[tx][k], b1 = Wsh[tx + 16][k], b2 = Wsh[tx + 32][k], b3 = Wsh[tx + 48][k];
        acc[0][0] += a0 * b0; acc[0][1] += a0 * b1; acc[0][2] += a0 * b2; acc[0][3] += a0 * b3;
        acc[1][0] += a1 * b0; acc[1][1] += a1 * b1; acc[1][2] += a1 * b2; acc[1][3] += a1 * b3;
        acc[2][0] += a2 * b0; acc[2][1] += a2 * b1; acc[2][2] += a2 * b2; acc[2][3] += a2 * b3;
        acc[3][0] += a3 * b0; acc[3][1] += a3 * b1; acc[3][2] += a3 * b2; acc[3][3] += a3 * b3;
    }
#pragma unroll
    for (int i = 0; i < 4; i++) {
        int s = sTile + ty + 16 * i;
#pragma unroll
        for (int j = 0; j < 4; j++) {
            int jj = jTile + tx + 16 * j;
            if (jj < NW) w[(size_t)s * WSTR + jj] = acc[i][j] + bv[jj];
        }
    }
}

// ---------------- Kernel C: scan, one site per wave ---------------------------
// 16-DEEP rolling prefetch (vbuf[16], 64 VGPR): consume-to-load distance ~16
// steps (~1400 cy wave-time) covers even HBM-latency returns. PRE layout is
// per-site contiguous rows: saddr(uniform) + voff(laundered s*row) + imm.
// sb=10 prefetch reaches t=365..367 = row pad (garbage, consumed only by
// masked-out steps); tail superblock needs NO prefetch at all.
template <bool PRE>
__global__ __launch_bounds__(256) void scan_kernel(const float* __restrict__ fx,
                                                   const float* __restrict__ w,
                                                   float* __restrict__ Y) {
    __shared__ float ybuf[4][64][33];   // 33,792 B per block
    const int wave = threadIdx.x >> 6;
    const int lane = threadIdx.x & 63;
    const int s = blockIdx.x * 4 + wave;
    const float* wr = w + (size_t)s * WSTR;

    // gate parameters (lane = hidden unit) — scalar loads OK (setup only)
    float gm = __expf(wr[lane]) + 1.0f;
    float geN = -2.0f * sigmoidf_(wr[64 + lane]);
    float k0 = sigmoidf_(wr[192 + lane]);
    float w4 = wr[256 + lane];
    float k1 = sigmoidf_(w4);
    float k2 = sigmoidf_(wr[320 + lane]);
    float gl = __expf(wr[384 + lane]);
    float kb = sigmoidf_(wr[448 + lane]) * 0.1f;
    float wl = wr[512];
    float qb = fmaxf(wl, 0.0f) * (1.0f / (float)NH);
    float vi = sigmoidf_(wl);

    // softmax over lanes -> ga
    float m = w4;
#pragma unroll
    for (int off = 32; off; off >>= 1) m = fmaxf(m, __shfl_xor(m, off));
    float ex = __expf(w4 - m);
    float sum = ex;
#pragma unroll
    for (int off = 32; off; off >>= 1) sum += __shfl_xor(sum, off);
    float ga = ex / sum;

    // folded coefficients
    float c0   = k0 * ga;
    float c1   = k1 * (1.0f - kb) * ga;
    float c2   = k2 * ga;
    float k0c  = 1.0f - k0;
    float k2c  = 1.0f - k2;
    float glN  = -gl;
    float viC  = 1.0f - vi;
    float k1kb = k1 * kb;    // G2 = fma(m1, k1kb, H2)
    float k1N  = -k1;        // H1 = min(fma(m1, k1N, G1), gl)

    float S0 = 0.f, H0 = 0.f, H1 = 0.f, H2 = 0.f;

    const char* fB = (const char*)fx;          // uniform SGPR base
    unsigned voff = PRE ? (unsigned)s * (FTR * 16u) : (unsigned)s * 16u;
    asm volatile("" : "+v"(voff));

    float4 vbuf[16];
#pragma unroll
    for (int b = 0; b < 16; b++) {
        if (PRE) vbuf[b] = *(const float4*)(fB + voff + b * 16);
        else     vbuf[b] = *(const float4*)(fB + (size_t)b * (NS * 16) + voff);
    }

    float* wp = &ybuf[wave][lane][0];                           // write: row h=lane
    const float* rp = &ybuf[wave][(lane >> 5) << 5][lane & 31]; // read: column

#define STEP_COMP(vv, tl)                                                      \
    {                                                                          \
        float Ps, Pl, E, TaR;                                                  \
        if (PRE) { Ps = vv.x; Pl = vv.y; E = vv.z; TaR = vv.w; }               \
        else {                                                                 \
            float P = vv.x; E = vv.y;                                          \
            float T1 = vv.z, T2 = vv.w;                                        \
            float Ta = 0.5f * (T1 + T2);                                       \
            float rP;                                                          \
            if (T2 <= 0.0f)      rP = 0.0f;                                    \
            else if (T1 >= 0.0f) rP = 1.0f;                                    \
            else rP = 1.0f - acosf((T1 + T2) / (T2 - T1)) * (1.0f / 3.1415f);  \
            Ps = (1.0f - rP) * P; Pl = rP * P; TaR = fmaxf(Ta, 0.0f);          \
        }                                                                      \
        float S   = S0 + Ps;                                                   \
        float Sm  = fminf(S0, gm * TaR);                                       \
        S0 = S - Sm;                                                           \
        float G1  = fmaxf(H1 + Sm + fmaf(E, geN, Pl * vi), 0.0f);              \
        float G0  = fmaxf(H0 + G1 + fmaf(Pl, viC, glN), 0.0f);                 \
        float m1  = fminf(G1, gl);                                             \
        float G2  = fmaf(m1, k1kb, H2);                                        \
        wp[tl] = fmaf(G0, c0, fmaf(m1, c1, G2 * c2));                          \
        H0 = G0 * k0c;                                                         \
        H1 = fminf(fmaf(m1, k1N, G1), gl);                                     \
        H2 = G2 * k2c;                                                         \
    }

#define TRRED(t0)                                                              \
    {                                                                          \
        float a0 = 0.f, a1 = 0.f, a2 = 0.f, a3 = 0.f;                          \
        _Pragma("unroll")                                                      \
        for (int j = 0; j < 32; j += 4) {                                      \
            a0 += rp[(size_t)j * 33];                                          \
            a1 += rp[(size_t)(j + 1) * 33];                                    \
            a2 += rp[(size_t)(j + 2) * 33];                                    \
            a3 += rp[(size_t)(j + 3) * 33];                                    \
        }                                                                      \
        float part = (a0 + a1) + (a2 + a3);                                    \
        float full = part + __shfl_xor(part, 32);                              \
        int t = (t0) + (lane & 31);                                            \
        if (lane < 32 && t < NT) Y[(size_t)t * NS + s] = full + qb;            \
    }

    // superblocks 0..10: prefetch t = sb*32 + tl + 16.
    // Max index = 10*32 + 31 + 16 = 367 <= FTR-1 (row pad); pad reads land in
    // slots consumed only by steps t>=365, whose stores are masked.
    for (int sb = 0; sb < 11; ++sb) {
        const char* fs = fB + sb * (32 * 16);       // uniform scalar advance
#pragma unroll
        for (int tl = 0; tl < 32; ++tl) {
            float4 v = vbuf[tl & 15];
            if (PRE)
                vbuf[tl & 15] = *(const float4*)(fs + voff + (tl + 16) * 16);
            else {
                int tn = sb * 32 + tl + 16; tn = tn < NT ? tn : NT - 1;
                vbuf[tl & 15] = *(const float4*)(fB + (size_t)tn * (NS * 16) + voff);
            }
            STEP_COMP(v, tl);
        }
        TRRED(sb * 32);
    }
    // tail superblock (t0=352): steps 352..364 consume slots prefetched during
    // sb=10; steps 365..383 consume stale/pad garbage, stores masked. No
    // prefetch needed at all.
    {
        const int t0 = 352;
#pragma unroll
        for (int tl = 0; tl < 32; ++tl) {
            float4 v = vbuf[tl & 15];
            STEP_COMP(v, tl);
        }
        TRRED(t0);
    }
#undef STEP_COMP
#undef TRRED
}

extern "C" void kernel_launch(void* const* d_in, const int* in_sizes, int n_in,
                              void* d_out, int out_size, void* d_ws, size_t ws_size,
                              hipStream_t stream) {
    const float* x  = (const float*)d_in[0];   // [NT, NS, 4]
    const float* xc = (const float*)d_in[1];   // [NS, NG]
    const float* Wm = (const float*)d_in[2];   // [NW, NG]
    const float* bv = (const float*)d_in[3];   // [NW]
    float* out = (float*)d_out;                // [NT, NS] fp32

    float* wbuf = (float*)d_ws;                                 // NS*WSTR floats
    size_t wbytes = (size_t)NS * WSTR * sizeof(float);          // 4,259,840 B
    float* fbuf = (float*)((char*)d_ws + wbytes);               // NS x FTR float4
    size_t need = wbytes + (size_t)NS * FTR * 16;               // ~16.3 MB

    if (ws_size >= need) {
        prep_kernel<<<256 + NS / 16, 256, 0, stream>>>(xc, Wm, bv, wbuf, x, fbuf);
        scan_kernel<true><<<NS / 4, 256, 0, stream>>>(fbuf, wbuf, out);
    } else {
        prep_kernel<<<256, 256, 0, stream>>>(xc, Wm, bv, wbuf, x, fbuf);  // gemm only
        scan_kernel<false><<<NS / 4, 256, 0, stream>>>(x, wbuf, out);
    }
}